// Round 1
// 286.639 us; speedup vs baseline: 1.3037x; 1.3037x over previous
//
#include <hip/hip_runtime.h>
#include <math.h>
#include <stdint.h>

// MoE: E=8, top-2, D=512, H=2048, N=4096, fp32 in/out.
// Round 7: atomic-free full-H expert kernel.
//   r6 counters: MfmaUtil 5.4%, WRITE_SIZE 134 MB (= 33.5M 4B atomic
//   write-throughs), stage->drain->compute steps expose full load latency.
//   v7 expert kernel: one block owns the FULL H=2048 reduction for 32 tokens
//   (y accumulator lives in 64 VGPR/thread across 8 H-slices), writes dense
//   f32 y rows (no atomics), prefetch double-buffered staging (1 barrier per
//   step, vmcnt drain lands after compute), expert->XCD affinity (e = b&7 so
//   each XCD's 4MB L2 holds exactly its expert's 4.2MB of bf16 weights).
//   combine kernel sums the 2 selected y rows per token (replaces memset).
//   Fallback chain: ws >= 56.4MB -> v7; >= 38.1MB -> r6 kernel; else fp32.

#define N_TOK 4096
#define D_IN  512
#define H_DIM 2048
#define N_EXP 8
#define TM    32
#define HS    256
#define MAXT  40                // covers cnt up to 1280 (expected ~1024)
#define YROWS (MAXT * TM)       // 1280 y slots per expert
#define HROW  264               // u16 stride: 528B rows, 16B-aligned, 132dw%32=4

typedef float  f32x4  __attribute__((ext_vector_type(4)));
typedef short  short8 __attribute__((ext_vector_type(8)));
typedef unsigned short u16;

__device__ __forceinline__ u16 bf16_rne(float f) {
    uint32_t u = __float_as_uint(f);
    return (u16)((u + 0x7fffu + ((u >> 16) & 1u)) >> 16);
}
__device__ __forceinline__ void async16(const u16* g, u16* l) {
    __builtin_amdgcn_global_load_lds(
        (const __attribute__((address_space(1))) void*)g,
        (__attribute__((address_space(3))) void*)l, 16, 0, 0);
}

// ---------------------------------------------------------------------------
// Gating: one wave per token. No atomics — writes (e1,e2),(g1,g2) records.
// Fused: converts x row to bf16 into xb (if write_xb).
// ---------------------------------------------------------------------------
__global__ __launch_bounds__(64) void moe_gate(
    const float* __restrict__ x, const float* __restrict__ Wg,
    const float* __restrict__ bg, float* __restrict__ gates,
    int2* __restrict__ recE, float2* __restrict__ recG,
    u16* __restrict__ xb, int write_xb)
{
    const int n = blockIdx.x;
    const int l = threadIdx.x;
    const float* xr  = x + (size_t)n * D_IN + l * 8;
    const float* wgr = Wg + (size_t)l * 8 * N_EXP;

    float xv[8];
    *(float4*)&xv[0] = *(const float4*)xr;
    *(float4*)&xv[4] = *(const float4*)(xr + 4);

    if (write_xb) {
        short8 pk;
#pragma unroll
        for (int i = 0; i < 8; ++i) pk[i] = (short)bf16_rne(xv[i]);
        *(short8*)(xb + (size_t)n * D_IN + l * 8) = pk;
    }

    float acc[8] = {0.f, 0.f, 0.f, 0.f, 0.f, 0.f, 0.f, 0.f};
#pragma unroll
    for (int dd = 0; dd < 8; ++dd) {
        float4 wa = *(const float4*)(wgr + dd * N_EXP);
        float4 wb = *(const float4*)(wgr + dd * N_EXP + 4);
        acc[0] = fmaf(xv[dd], wa.x, acc[0]);
        acc[1] = fmaf(xv[dd], wa.y, acc[1]);
        acc[2] = fmaf(xv[dd], wa.z, acc[2]);
        acc[3] = fmaf(xv[dd], wa.w, acc[3]);
        acc[4] = fmaf(xv[dd], wb.x, acc[4]);
        acc[5] = fmaf(xv[dd], wb.y, acc[5]);
        acc[6] = fmaf(xv[dd], wb.z, acc[6]);
        acc[7] = fmaf(xv[dd], wb.w, acc[7]);
    }
#pragma unroll
    for (int off = 32; off >= 1; off >>= 1) {
#pragma unroll
        for (int e = 0; e < N_EXP; ++e)
            acc[e] += __shfl_xor(acc[e], off);
    }

    float g[8];
    float mx = -3.4e38f;
#pragma unroll
    for (int e = 0; e < N_EXP; ++e) { g[e] = acc[e] + bg[e]; mx = fmaxf(mx, g[e]); }
    float s = 0.f;
#pragma unroll
    for (int e = 0; e < N_EXP; ++e) { g[e] = expf(g[e] - mx); s += g[e]; }
    const float inv = 1.0f / s;
#pragma unroll
    for (int e = 0; e < N_EXP; ++e) g[e] *= inv;

    if (l == 0) {
        float* go = gates + (size_t)n * N_EXP;
        *(float4*)go       = make_float4(g[0], g[1], g[2], g[3]);
        *(float4*)(go + 4) = make_float4(g[4], g[5], g[6], g[7]);

        int e1 = 0; float g1 = g[0];
#pragma unroll
        for (int e = 1; e < N_EXP; ++e) if (g[e] > g1) { g1 = g[e]; e1 = e; }
        int e2 = -1; float g2 = -1.f;
#pragma unroll
        for (int e = 0; e < N_EXP; ++e) if (e != e1 && g[e] > g2) { g2 = g[e]; e2 = e; }

        recE[n] = make_int2(e1, e2);
        recG[n] = make_float2(g1, g2);
    }
}

// ---------------------------------------------------------------------------
// List build: block e scans all records, LDS-atomic compaction.
// Also records the slot index per (token, k) for the combine kernel.
// ---------------------------------------------------------------------------
__global__ __launch_bounds__(256) void build_lists(
    const int2* __restrict__ recE, const float2* __restrict__ recG,
    int* __restrict__ counts, int* __restrict__ lists, float* __restrict__ cwA,
    int* __restrict__ slotRec)
{
    __shared__ int cnt;
    const int e = blockIdx.x;
    const int tid = threadIdx.x;
    if (tid == 0) cnt = 0;
    __syncthreads();
    for (int t = tid; t < N_TOK; t += 256) {
        int2   ee = recE[t];
        float2 gg = recG[t];
        if (ee.x == e) {
            int p = atomicAdd(&cnt, 1);
            lists[e * N_TOK + p] = t;  cwA[e * N_TOK + p] = gg.x;
            if (slotRec) slotRec[2 * t + 0] = p;
        }
        if (ee.y == e) {
            int p = atomicAdd(&cnt, 1);
            lists[e * N_TOK + p] = t;  cwA[e * N_TOK + p] = gg.y;
            if (slotRec) slotRec[2 * t + 1] = p;
        }
    }
    __syncthreads();
    if (tid == 0) counts[e] = cnt;
}

// ---------------------------------------------------------------------------
// Prep: tiled transpose to bf16, W1 and W2 in one launch.
// z<8: W1[e][D][H] -> w1t[e][H][D];  z>=8: W2[e][H][D] -> w2t[e][D][H].
// grid (32, 8, 16): exact tile cover for both shapes (roles of x/y swapped).
// ---------------------------------------------------------------------------
__global__ __launch_bounds__(256) void conv_w_both(
    const float* __restrict__ W1, const float* __restrict__ W2,
    u16* __restrict__ w1t, u16* __restrict__ w2t)
{
    __shared__ u16 th[64][65];
    const int z  = blockIdx.z;
    const int e  = z & 7;
    const bool isW2 = z >= 8;
    const float* in = isW2 ? W2 : W1;
    u16* ob         = isW2 ? w2t : w1t;
    const int R = isW2 ? H_DIM : D_IN;
    const int C = isW2 ? D_IN : H_DIM;
    const size_t base = (size_t)e * R * C;
    const int c0 = (isW2 ? blockIdx.y : blockIdx.x) * 64;
    const int r0 = (isW2 ? blockIdx.x : blockIdx.y) * 64;
    const int c  = threadIdx.x & 63, rq = threadIdx.x >> 6;

#pragma unroll
    for (int i = 0; i < 16; ++i) {
        int r = rq * 16 + i;
        th[r][c] = bf16_rne(in[base + (size_t)(r0 + r) * C + c0 + c]);
    }
    __syncthreads();
#pragma unroll
    for (int i = 0; i < 16; ++i) {
        int rw = rq * 16 + i;
        ob[base + (size_t)(c0 + rw) * R + r0 + c] = th[c][rw];
    }
}

// ---------------------------------------------------------------------------
// v7 expert kernel: full-H per block, 256 threads (4 waves), grid 8*MAXT.
//   e = blockIdx&7 (XCD affinity), t = blockIdx>>3.
//   per si in 0..7:  G1 (16 steps, BK=32) -> hT(32x256 bf16) -> G2 (16 steps)
//   accumulating y[32][512] in registers (accY[4][2][2] f32x4 = 64 f32).
//   Staging: prefetch double-buffer, ONE barrier per step; buffer index is
//   compile-time (ks&1 / u&1; 32 flips per si returns parity to 0).
//   Dense y stores (x cw, +b2) — zero atomics.
// LDS: sB 32KB dbuf + sA 4KB dbuf + hT 16.5KB = ~53KB.
// ---------------------------------------------------------------------------
#define STG_G1(si_, ks_, buf_)                                                \
    do {                                                                      \
        const u16* _s = w1E + (size_t)(si_) * (HS * D_IN) + (ks_) * 32;       \
        _Pragma("unroll")                                                     \
        for (int _i = 0; _i < 4; ++_i)                                        \
            async16(_s + bOffB[_i], &sB[buf_][dstB + _i * 512]);              \
        if (w < 2)                                                            \
            async16(xb + aOffW + (ks_) * 32, &sA[buf_][w * 512 + lane * 8]);  \
    } while (0)

#define STG_G2(si_, u_, buf_)                                                 \
    do {                                                                      \
        const int _nc = (u_) >> 2, _k2 = (u_) & 3;                            \
        const u16* _s = w2E + (size_t)_nc * (128 * H_DIM) + (si_) * HS + _k2 * 64; \
        _Pragma("unroll")                                                     \
        for (int _i = 0; _i < 4; ++_i)                                        \
            async16(_s + bOff2[_i], &sB[buf_][dstB + _i * 512]);              \
    } while (0)

__global__ __launch_bounds__(256, 2) void moe_expert_mfma2(
    const u16* __restrict__ xb,
    const u16* __restrict__ w1t, const u16* __restrict__ w2t,
    const float* __restrict__ b1, const float* __restrict__ b2,
    float* __restrict__ y,
    const int* __restrict__ counts, const int* __restrict__ lists,
    const float* __restrict__ cwA)
{
    const int b = blockIdx.x;
    const int e = b & 7;            // expert -> XCD affinity
    const int t = b >> 3;
    int cnt = counts[e];
    if (cnt > YROWS) cnt = YROWS;
    if (t * TM >= cnt) return;

    __shared__ __align__(16) u16 sB[2][8192];    // 32 KB: dbuf 16KB chunks
    __shared__ __align__(16) u16 sA[2][1024];    //  4 KB: dbuf x chunks
    __shared__ __align__(16) u16 hT[TM * HROW];  // 16.5 KB
    __shared__ int   tokS[TM];
    __shared__ float cwS[TM];

    const int tid  = threadIdx.x;
    const int w    = tid >> 6;
    const int lane = tid & 63;
    const int quad = lane >> 4;
    const int l16  = lane & 15;

    if (tid < TM) {
        int gi = t * TM + tid;
        bool v = gi < cnt;
        tokS[tid] = v ? lists[e * N_TOK + gi] : 0;
        cwS[tid]  = v ? cwA[e * N_TOK + gi] : 0.f;   // cw=0 kills pad rows
    }
    __syncthreads();

    // ---- staging geometry (lds dest = wave base + lane*16B) ----
    const int r4   = lane >> 2;                       // G1: 16 rows/inst
    const int csw1 = (lane & 3) ^ ((lane >> 4) & 3);  // key=(rowInChunk>>2)&3
    const int r8   = lane >> 3;                       // G2: 8 rows/inst
    const int csw2 = (lane & 7) ^ r8;                 // key=rowInChunk&7
    const int dstB = w * 2048 + lane * 8;             // u16 offset in sB buf

    // ---- fragment read offsets (u16 elements, within a buffer) ----
    int fB1[4], fA1[2];
#pragma unroll
    for (int nt = 0; nt < 4; ++nt) {
        int r = w * 64 + nt * 16 + l16;
        fB1[nt] = r * 32 + (quad ^ ((l16 >> 2) & 3)) * 8;
    }
#pragma unroll
    for (int m = 0; m < 2; ++m) {
        int r = m * 16 + l16;
        fA1[m] = r * 32 + (quad ^ ((l16 >> 2) & 3)) * 8;
    }
    int fB2[2][2], fA2[2];
#pragma unroll
    for (int nt = 0; nt < 2; ++nt)
#pragma unroll
        for (int kk = 0; kk < 2; ++kk) {
            int r = w * 32 + nt * 16 + l16;
            fB2[nt][kk] = r * 64 + (((kk * 4 + quad) ^ (l16 & 7)) * 8);
        }
#pragma unroll
    for (int m = 0; m < 2; ++m)
        fA2[m] = (m * 16 + l16) * HROW + quad * 8;

    // ---- global staging offsets ----
    const u16* w1E = w1t + (size_t)e * H_DIM * D_IN;
    const u16* w2E = w2t + (size_t)e * D_IN * H_DIM;
    int bOffB[4];
#pragma unroll
    for (int i = 0; i < 4; ++i)
        bOffB[i] = (w * 64 + i * 16 + r4) * D_IN + csw1 * 8;
    int bOff2[4];
#pragma unroll
    for (int i = 0; i < 4; ++i)
        bOff2[i] = (w * 32 + i * 8 + r8) * H_DIM + csw2 * 8;
    int aOffW = 0;
    if (w < 2) aOffW = tokS[w * 16 + r4] * D_IN + csw1 * 8;

    // ---- persistent output accumulator: y[32][512] across all si ----
    f32x4 accY[4][2][2];
#pragma unroll
    for (int nc = 0; nc < 4; ++nc)
#pragma unroll
        for (int m = 0; m < 2; ++m)
#pragma unroll
            for (int nt = 0; nt < 2; ++nt)
                accY[nc][m][nt] = (f32x4){0.f, 0.f, 0.f, 0.f};

    // prologue: stage (si=0, ks=0) into buffer 0
    STG_G1(0, 0, 0);
    __syncthreads();

    for (int si = 0; si < 8; ++si) {
        // -------- GEMM1: h[32][256] = xb-tile @ W1T-slice(si) --------
        f32x4 acc1[2][4];
#pragma unroll
        for (int m = 0; m < 2; ++m)
#pragma unroll
            for (int nt = 0; nt < 4; ++nt) acc1[m][nt] = (f32x4){0.f, 0.f, 0.f, 0.f};

#pragma unroll
        for (int ks = 0; ks < 16; ++ks) {
            if (ks < 15) { STG_G1(si, ks + 1, (ks + 1) & 1); }
            else         { STG_G2(si, 0, 0); }       // (15+1)&1 == 0
            const u16* Bp = &sB[ks & 1][0];
            const u16* Ap = &sA[ks & 1][0];
            short8 bf[4], af[2];
#pragma unroll
            for (int nt = 0; nt < 4; ++nt) bf[nt] = *(const short8*)(Bp + fB1[nt]);
#pragma unroll
            for (int m = 0; m < 2; ++m)  af[m] = *(const short8*)(Ap + fA1[m]);
#pragma unroll
            for (int nt = 0; nt < 4; ++nt)
#pragma unroll
                for (int m = 0; m < 2; ++m)
                    acc1[m][nt] = __builtin_amdgcn_mfma_f32_16x16x32_bf16(
                        af[m], bf[nt], acc1[m][nt], 0, 0, 0);
            __syncthreads();   // drains staged loads; all waves done with cur
        }

        // -------- epilogue 1: bias + relu -> hT (bf16) --------
#pragma unroll
        for (int nt = 0; nt < 4; ++nt) {
            const int c = w * 64 + nt * 16 + l16;
            const float bias = b1[e * H_DIM + si * HS + c];
#pragma unroll
            for (int m = 0; m < 2; ++m)
#pragma unroll
                for (int r = 0; r < 4; ++r) {
                    int row = m * 16 + quad * 4 + r;
                    hT[row * HROW + c] = bf16_rne(fmaxf(acc1[m][nt][r] + bias, 0.f));
                }
        }
        __syncthreads();       // hT visible before G2 reads

        // -------- GEMM2: accY += hT @ W2T-slice(si) --------
#pragma unroll
        for (int u = 0; u < 16; ++u) {
            const int nc = u >> 2, k2 = u & 3;
            if (u < 15)      { STG_G2(si, u + 1, (u + 1) & 1); }
            else if (si < 7) { STG_G1(si + 1, 0, 0); }   // (15+1)&1 == 0
            const u16* Bp = &sB[u & 1][0];
#pragma unroll
            for (int kk = 0; kk < 2; ++kk) {
                short8 a0  = *(const short8*)(hT + fA2[0] + k2 * 64 + kk * 32);
                short8 a1  = *(const short8*)(hT + fA2[1] + k2 * 64 + kk * 32);
                short8 b0  = *(const short8*)(Bp + fB2[0][kk]);
                short8 b1f = *(const short8*)(Bp + fB2[1][kk]);
                accY[nc][0][0] = __builtin_amdgcn_mfma_f32_16x16x32_bf16(a0, b0,  accY[nc][0][0], 0, 0, 0);
                accY[nc][1][0] = __builtin_amdgcn_mfma_f32_16x16x32_bf16(a1, b0,  accY[nc][1][0], 0, 0, 0);
                accY[nc][0][1] = __builtin_amdgcn_mfma_f32_16x16x32_bf16(a0, b1f, accY[nc][0][1], 0, 0, 0);
                accY[nc][1][1] = __builtin_amdgcn_mfma_f32_16x16x32_bf16(a1, b1f, accY[nc][1][1], 0, 0, 0);
            }
            __syncthreads();
        }
    }

    // -------- epilogue: dense y write: (acc + b2) * cw --------
    float* yT = y + ((size_t)e * YROWS + (size_t)t * TM) * D_IN;
#pragma unroll
    for (int nc = 0; nc < 4; ++nc)
#pragma unroll
        for (int nt = 0; nt < 2; ++nt) {
            const int dcol = nc * 128 + w * 32 + nt * 16 + l16;
            const float bias = b2[e * D_IN + dcol];
#pragma unroll
            for (int m = 0; m < 2; ++m)
#pragma unroll
                for (int r = 0; r < 4; ++r) {
                    const int row = m * 16 + quad * 4 + r;
                    yT[(size_t)row * D_IN + dcol] =
                        (accY[nc][m][nt][r] + bias) * cwS[row];
                }
        }
}

// ---------------------------------------------------------------------------
// Combine: out[t] = y[e1][slot1] + y[e2][slot2]   (cw, b2 already folded in).
// 2 tokens per 256-thread block; float4 per thread. Fully writes out.
// ---------------------------------------------------------------------------
__global__ __launch_bounds__(256) void moe_combine(
    const float* __restrict__ y, const int* __restrict__ slotRec,
    const int2* __restrict__ recE, float* __restrict__ out)
{
    const int t  = blockIdx.x * 2 + (threadIdx.x >> 7);
    const int c4 = (threadIdx.x & 127) << 2;
    const int2 ee = recE[t];
    int s1 = slotRec[2 * t + 0];
    int s2 = slotRec[2 * t + 1];
    s1 = s1 < YROWS ? s1 : YROWS - 1;   // safety clamp (cnt overflow impossible in practice)
    s2 = s2 < YROWS ? s2 : YROWS - 1;
    const float4 a  = *(const float4*)(y + ((size_t)ee.x * YROWS + s1) * D_IN + c4);
    const float4 bb = *(const float4*)(y + ((size_t)ee.y * YROWS + s2) * D_IN + c4);
    *(float4*)(out + (size_t)t * D_IN + c4) =
        make_float4(a.x + bb.x, a.y + bb.y, a.z + bb.z, a.w + bb.w);
}

// ---------------------------------------------------------------------------
// r6 single-pass bf16 expert kernel (known-passing) — fallback if ws < NEED2.
// ---------------------------------------------------------------------------
__global__ __launch_bounds__(256, 4) void moe_expert_mfma(
    const u16* __restrict__ xb,
    const u16* __restrict__ w1t, const u16* __restrict__ w2t,
    const float* __restrict__ b1, const float* __restrict__ b2,
    float* __restrict__ out,
    const int* __restrict__ counts, const int* __restrict__ lists,
    const float* __restrict__ cwA)
{
    const int b = blockIdx.x;
    const int s = b & 7;
    const int q = b >> 3;
    const int t = q % MAXT;
    const int e = q / MAXT;
    const int cnt = counts[e];
    if (t * TM >= cnt) return;

    __shared__ __align__(16) u16 sB[8192];
    __shared__ __align__(16) u16 sA[1024];
    __shared__ __align__(16) u16 hT[TM * HROW];
    __shared__ int   tokS[TM];
    __shared__ float cwS[TM];

    const int tid  = threadIdx.x;
    const int w    = tid >> 6;
    const int lane = tid & 63;
    const int quad = lane >> 4;
    const int l16  = lane & 15;

    if (tid < TM) {
        int gi = t * TM + tid;
        bool v = gi < cnt;
        tokS[tid] = v ? lists[e * N_TOK + gi] : 0;
        cwS[tid]  = v ? cwA[e * N_TOK + gi] : 0.f;
    }
    __syncthreads();

    const int r4   = lane >> 2;
    const int csw1 = (lane & 3) ^ ((lane >> 4) & 3);
    const int r8   = lane >> 3;
    const int csw2 = (lane & 7) ^ r8;
    u16* ldsB0 = sB + w * 2048 + lane * 8;
    u16* ldsA0 = sA + lane * 8;

    int fB1[4], fA1[2];
#pragma unroll
    for (int nt = 0; nt < 4; ++nt) {
        int r = w * 64 + nt * 16 + l16;
        fB1[nt] = r * 32 + (quad ^ ((l16 >> 2) & 3)) * 8;
    }
#pragma unroll
    for (int m = 0; m < 2; ++m) {
        int r = m * 16 + l16;
        fA1[m] = r * 32 + (quad ^ ((l16 >> 2) & 3)) * 8;
    }
    int fB2[2][2], fA2[2];
#pragma unroll
    for (int nt = 0; nt < 2; ++nt)
#pragma unroll
        for (int kk = 0; kk < 2; ++kk) {
            int r = w * 32 + nt * 16 + l16;
            fB2[nt][kk] = r * 64 + (((kk * 4 + quad) ^ (l16 & 7)) * 8);
        }
#pragma unroll
    for (int m = 0; m < 2; ++m)
        fA2[m] = (m * 16 + l16) * HROW + quad * 8;

    int bOffB[4];
#pragma unroll
    for (int i = 0; i < 4; ++i)
        bOffB[i] = (s * HS + w * 64 + i * 16 + r4) * D_IN + csw1 * 8;
    int aOff0 = tokS[r4]      * D_IN + csw1 * 8;
    int aOff1 = tokS[16 + r4] * D_IN + csw1 * 8;
    const u16* w1E = w1t + (size_t)e * H_DIM * D_IN;

    f32x4 acc1[2][4];
#pragma unroll
    for (int m = 0; m < 2; ++m)
#pragma unroll
        for (int nt = 0; nt < 4; ++nt) acc1[m][nt] = (f32x4){0.f, 0.f, 0.f, 0.f};

    for (int ks = 0; ks < 16; ++ks) {
        const int kb = ks * 32;
        __syncthreads();
#pragma unroll
        for (int i = 0; i < 4; ++i)
            async16(w1E + bOffB[i] + kb, ldsB0 + i * 512);
        if (w == 0) {
            async16(xb + aOff0 + kb, ldsA0);
            async16(xb + aOff1 + kb, ldsA0 + 512);
        }
        __syncthreads();
        short8 bf[4], af[2];
#pragma unroll
        for (int nt = 0; nt < 4; ++nt) bf[nt] = *(const short8*)(sB + fB1[nt]);
#pragma unroll
        for (int m = 0; m < 2; ++m)  af[m] = *(const short8*)(sA + fA1[m]);
#pragma unroll
        for (int nt = 0; nt < 4; ++nt)
#pragma unroll
            for (int m = 0; m < 2; ++m)
                acc1[m][nt] = __builtin_amdgcn_mfma_f32_16x16x32_bf16(af[m], bf[nt], acc1[m][nt], 0, 0, 0);
    }

#pragma unroll
    for (int nt = 0; nt < 4; ++nt) {
        const int c = w * 64 + nt * 16 + l16;
        const float bias = b1[e * H_DIM + s * HS + c];
#pragma unroll
        for (int m = 0; m < 2; ++m)
#pragma unroll
            for (int r = 0; r < 4; ++r) {
                int row = m * 16 + quad * 4 + r;
                hT[row * HROW + c] = bf16_rne(fmaxf(acc1[m][nt][r] + bias, 0.f));
            }
    }

    const u16* w2E = w2t + (size_t)e * D_IN * H_DIM;
    int bOff2[4];
#pragma unroll
    for (int i = 0; i < 4; ++i)
        bOff2[i] = (w * 32 + i * 8 + r8) * H_DIM + s * HS + csw2 * 8;

    for (int nc = 0; nc < 4; ++nc) {
        f32x4 acc2[2][2];
#pragma unroll
        for (int m = 0; m < 2; ++m)
#pragma unroll
            for (int nt = 0; nt < 2; ++nt) acc2[m][nt] = (f32x4){0.f, 0.f, 0.f, 0.f};

        for (int ks = 0; ks < 4; ++ks) {
            __syncthreads();
#pragma unroll
            for (int i = 0; i < 4; ++i)
                async16(w2E + bOff2[i] + nc * (128 * H_DIM) + ks * 64,
                        ldsB0 + i * 512);
            __syncthreads();
#pragma unroll
            for (int kk = 0; kk < 2; ++kk) {
                short8 a0  = *(const short8*)(hT + fA2[0] + ks * 64 + kk * 32);
                short8 a1  = *(const short8*)(hT + fA2[1] + ks * 64 + kk * 32);
                short8 b0  = *(const short8*)(sB + fB2[0][kk]);
                short8 b1f = *(const short8*)(sB + fB2[1][kk]);
                acc2[0][0] = __builtin_amdgcn_mfma_f32_16x16x32_bf16(a0, b0,  acc2[0][0], 0, 0, 0);
                acc2[1][0] = __builtin_amdgcn_mfma_f32_16x16x32_bf16(a1, b0,  acc2[1][0], 0, 0, 0);
                acc2[0][1] = __builtin_amdgcn_mfma_f32_16x16x32_bf16(a0, b1f, acc2[0][1], 0, 0, 0);
                acc2[1][1] = __builtin_amdgcn_mfma_f32_16x16x32_bf16(a1, b1f, acc2[1][1], 0, 0, 0);
            }
        }

#pragma unroll
        for (int nt = 0; nt < 2; ++nt) {
            const int dcol = nc * 128 + w * 32 + nt * 16 + l16;
            const float bias = (s == 0) ? b2[e * D_IN + dcol] : 0.f;
#pragma unroll
            for (int m = 0; m < 2; ++m)
#pragma unroll
                for (int r = 0; r < 4; ++r) {
                    int row = m * 16 + quad * 4 + r;
                    float v = (acc2[m][nt][r] + bias) * cwS[row];
                    atomicAdd(out + (size_t)tokS[row] * D_IN + dcol, v);
                }
        }
    }
}

// ---------------------------------------------------------------------------
// Fallback fp32 expert kernel (round 1, known-passing) — used if ws too small.
// ---------------------------------------------------------------------------
__global__ __launch_bounds__(256, 4) void moe_expert_fp32(
    const float* __restrict__ x,  const float* __restrict__ W1,
    const float* __restrict__ b1, const float* __restrict__ W2,
    const float* __restrict__ b2, float* __restrict__ out,
    const int* __restrict__ counts, const int* __restrict__ lists,
    const float* __restrict__ cwA)
{
    const int e    = blockIdx.x & 7;
    const int tile = blockIdx.x >> 3;
    const int cnt  = counts[e];
    if (tile * 16 >= cnt) return;

    __shared__ float xs[16 * 520];
    __shared__ float hs[16 * 68];
    __shared__ int   tokS[16];
    __shared__ float cwS[16];

    const int tid = threadIdx.x;
    if (tid < 16) {
        int gi = tile * 16 + tid;
        bool v = gi < cnt;
        tokS[tid] = v ? lists[e * N_TOK + gi] : 0;
        cwS[tid]  = v ? cwA[e * N_TOK + gi]  : 0.f;
    }
    __syncthreads();
    {
        const int i = tid >> 4, p = tid & 15;
        const float* xr = x + (size_t)tokS[i] * D_IN + p * 32;
        float* xd = xs + i * 520 + p * 32;
#pragma unroll
        for (int qq = 0; qq < 8; ++qq)
            *(float4*)(xd + qq * 4) = *(const float4*)(xr + qq * 4);
    }
    __syncthreads();

    const float* W1e = W1 + (size_t)e * D_IN * H_DIM;
    const float* W2e = W2 + (size_t)e * H_DIM * D_IN;
    const int j = tid & 31, rg1 = tid >> 5, cg = tid & 63, rg2 = tid >> 6;

    float acc[4][8];
#pragma unroll
    for (int i = 0; i < 4; ++i)
#pragma unroll
        for (int m = 0; m < 8; ++m) acc[i][m] = 0.f;

    for (int hc = 0; hc < H_DIM / 64; ++hc) {
        float a1[2][2] = {{0.f, 0.f}, {0.f, 0.f}};
        const float* w1p = W1e + hc * 64 + j;
        for (int d = 0; d < D_IN; d += 4) {
            float xv[2][4];
            *(float4*)xv[0] = *(const float4*)(xs + (rg1 * 2 + 0) * 520 + d);
            *(float4*)xv[1] = *(const float4*)(xs + (rg1 * 2 + 1) * 520 + d);
#pragma unroll
            for (int dd = 0; dd < 4; ++dd) {
                float wa = w1p[(size_t)(d + dd) * H_DIM];
                float wb = w1p[(size_t)(d + dd) * H_DIM + 32];
                a1[0][0] = fmaf(xv[0][dd], wa, a1[0][0]);
                a1[0][1] = fmaf(xv[0][dd], wb, a1[0][1]);
                a1[1][0] = fmaf(xv[1][dd], wa, a1[1][0]);
                a1[1][1] = fmaf(xv[1][dd], wb, a1[1][1]);
            }
        }
        float b1a = b1[e * H_DIM + hc * 64 + j];
        float b1b = b1[e * H_DIM + hc * 64 + j + 32];
        __syncthreads();
        hs[(rg1 * 2 + 0) * 68 + j]      = fmaxf(a1[0][0] + b1a, 0.f);
        hs[(rg1 * 2 + 0) * 68 + j + 32] = fmaxf(a1[0][1] + b1b, 0.f);
        hs[(rg1 * 2 + 1) * 68 + j]      = fmaxf(a1[1][0] + b1a, 0.f);
        hs[(rg1 * 2 + 1) * 68 + j + 32] = fmaxf(a1[1][1] + b1b, 0.f);
        __syncthreads();
        const float* w2p = W2e + (size_t)(hc * 64) * D_IN + cg;
        for (int k = 0; k < 64; k += 4) {
            float hv[4][4];
#pragma unroll
            for (int i = 0; i < 4; ++i)
                *(float4*)hv[i] = *(const float4*)(hs + (rg2 * 4 + i) * 68 + k);
#pragma unroll
            for (int kk = 0; kk < 4; ++kk) {
                float w2r[8];
#pragma unroll
                for (int m = 0; m < 8; ++m)
                    w2r[m] = w2p[(size_t)(k + kk) * D_IN + 64 * m];
#pragma unroll
                for (int i = 0; i < 4; ++i)
#pragma unroll
                    for (int m = 0; m < 8; ++m)
                        acc[i][m] = fmaf(hv[i][kk], w2r[m], acc[i][m]);
            }
        }
        __syncthreads();
    }
    float b2v[8];
#pragma unroll
    for (int m = 0; m < 8; ++m) b2v[m] = b2[e * D_IN + cg + 64 * m];
#pragma unroll
    for (int i = 0; i < 4; ++i) {
        const int r = rg2 * 4 + i;
        const float cw = cwS[r];
        float* op = out + (size_t)tokS[r] * D_IN + cg;
#pragma unroll
        for (int m = 0; m < 8; ++m)
            atomicAdd(op + 64 * m, (acc[i][m] + b2v[m]) * cw);
    }
}

// ---------------------------------------------------------------------------
extern "C" void kernel_launch(void* const* d_in, const int* in_sizes, int n_in,
                              void* d_out, int out_size, void* d_ws, size_t ws_size,
                              hipStream_t stream) {
    const float* x  = (const float*)d_in[0];
    const float* Wg = (const float*)d_in[1];
    const float* bg = (const float*)d_in[2];
    const float* W1 = (const float*)d_in[3];
    const float* b1 = (const float*)d_in[4];
    const float* W2 = (const float*)d_in[5];
    const float* b2 = (const float*)d_in[6];

    float* out   = (float*)d_out;
    float* gates = out + (size_t)N_TOK * D_IN;

    // ws layout: counts | recE | recG | lists | cw | xb | w1t | w2t | slot | y
    // (prefix through w2t identical to r6 so the fallback threshold is unchanged)
    const size_t o_recE  = 1024;
    const size_t o_recG  = o_recE + (size_t)N_TOK * 8;
    const size_t o_lists = o_recG + (size_t)N_TOK * 8;
    const size_t o_cw    = o_lists + (size_t)N_EXP * N_TOK * 4;
    const size_t o_xb    = o_cw + (size_t)N_EXP * N_TOK * 4;
    const size_t o_w1t   = o_xb + (size_t)N_TOK * D_IN * 2;
    const size_t o_w2t   = o_w1t + (size_t)N_EXP * D_IN * H_DIM * 2;
    const size_t o_slot  = o_w2t + (size_t)N_EXP * D_IN * H_DIM * 2;
    const size_t o_y     = o_slot + (size_t)N_TOK * 2 * 4;
    const size_t NEED1   = o_slot;                                   // ~38.1 MB
    const size_t NEED2   = o_y + (size_t)N_EXP * YROWS * D_IN * 4;   // ~56.4 MB

    int*    counts  = (int*)d_ws;
    int2*   recE    = (int2*)((char*)d_ws + o_recE);
    float2* recG    = (float2*)((char*)d_ws + o_recG);
    int*    lists   = (int*)((char*)d_ws + o_lists);
    float*  cwA     = (float*)((char*)d_ws + o_cw);
    u16*    xb      = (u16*)((char*)d_ws + o_xb);
    u16*    w1t     = (u16*)((char*)d_ws + o_w1t);
    u16*    w2t     = (u16*)((char*)d_ws + o_w2t);
    int*    slotRec = (int*)((char*)d_ws + o_slot);
    float*  yws     = (float*)((char*)d_ws + o_y);

    const int mode = (ws_size >= NEED2) ? 2 : (ws_size >= NEED1 ? 1 : 0);

    moe_gate<<<N_TOK, 64, 0, stream>>>(x, Wg, bg, gates, recE, recG, xb,
                                       mode >= 1 ? 1 : 0);
    build_lists<<<N_EXP, 256, 0, stream>>>(recE, recG, counts, lists, cwA,
                                           mode == 2 ? slotRec : (int*)nullptr);

    if (mode == 2) {
        conv_w_both<<<dim3(32, 8, 16), 256, 0, stream>>>(W1, W2, w1t, w2t);
        moe_expert_mfma2<<<N_EXP * MAXT, 256, 0, stream>>>(
            xb, w1t, w2t, b1, b2, yws, counts, lists, cwA);
        moe_combine<<<N_TOK / 2, 256, 0, stream>>>(yws, slotRec, recE, out);
    } else if (mode == 1) {
        hipMemsetAsync(d_out, 0, (size_t)N_TOK * D_IN * sizeof(float), stream);
        conv_w_both<<<dim3(32, 8, 16), 256, 0, stream>>>(W1, W2, w1t, w2t);
        moe_expert_mfma<<<N_EXP * MAXT * 8, 256, 0, stream>>>(
            xb, w1t, w2t, b1, b2, out, counts, lists, cwA);
    } else {
        hipMemsetAsync(d_out, 0, (size_t)N_TOK * D_IN * sizeof(float), stream);
        moe_expert_fp32<<<N_EXP * 256, 256, 0, stream>>>(
            x, W1, b1, W2, b2, out, counts, lists, cwA);
    }
}

// Round 2
// 283.577 us; speedup vs baseline: 1.3178x; 1.0108x over previous
//
#include <hip/hip_runtime.h>
#include <math.h>
#include <stdint.h>

// MoE: E=8, top-2, D=512, H=2048, N=4096, fp32 in/out.
// Round 8: counted-vmcnt pipelined expert kernel (T3/T4).
//   r7 counters: MfmaUtil 8.8% -- __syncthreads() drains vmcnt(0) each step,
//   so the double-buffer prefetch never overlapped. v8 expert kernel:
//   triple-buffered 16KB stage chunks, per step {asm s_waitcnt vmcnt(5/4);
//   raw s_barrier; sched_barrier(0); stage group u+2; 8 MFMA} -- loads stay
//   in flight across 2 steps + 2 barriers. Per-si drain (vmcnt(0)) only at
//   slice boundaries (8x ~400cy bubble). setprio(1) around MFMA (T5).
//   LDS ~71KB -> 2 blocks/CU for cross-block TLP.
//   Also: gate fused into prep launch (runs concurrently with transpose),
//   build_lists parallelized 8->64 blocks (global atomicAdd base).

#define N_TOK 4096
#define D_IN  512
#define H_DIM 2048
#define N_EXP 8
#define TM    32
#define HS    256
#define MAXT  40                // covers cnt up to 1280 (expected ~1024)
#define YROWS (MAXT * TM)       // 1280 y slots per expert
#define HROW  264               // u16 stride: 528B rows, 16B-aligned, 132dw%32=4

typedef float  f32x4  __attribute__((ext_vector_type(4)));
typedef short  short8 __attribute__((ext_vector_type(8)));
typedef unsigned short u16;

__device__ __forceinline__ u16 bf16_rne(float f) {
    uint32_t u = __float_as_uint(f);
    return (u16)((u + 0x7fffu + ((u >> 16) & 1u)) >> 16);
}
__device__ __forceinline__ void async16(const u16* g, u16* l) {
    __builtin_amdgcn_global_load_lds(
        (const __attribute__((address_space(1))) void*)g,
        (__attribute__((address_space(3))) void*)l, 16, 0, 0);
}

// ---------------------------------------------------------------------------
// Gate body: one wave per token. Writes gates row + top-2 records; optionally
// converts the x row to bf16 into xb.
// ---------------------------------------------------------------------------
__device__ __forceinline__ void gate_one(
    int n, int l,
    const float* __restrict__ x, const float* __restrict__ Wg,
    const float* __restrict__ bg, float* __restrict__ gates,
    int2* __restrict__ recE, float2* __restrict__ recG,
    u16* __restrict__ xb, int write_xb)
{
    const float* xr  = x + (size_t)n * D_IN + l * 8;
    const float* wgr = Wg + (size_t)l * 8 * N_EXP;

    float xv[8];
    *(float4*)&xv[0] = *(const float4*)xr;
    *(float4*)&xv[4] = *(const float4*)(xr + 4);

    if (write_xb) {
        short8 pk;
#pragma unroll
        for (int i = 0; i < 8; ++i) pk[i] = (short)bf16_rne(xv[i]);
        *(short8*)(xb + (size_t)n * D_IN + l * 8) = pk;
    }

    float acc[8] = {0.f, 0.f, 0.f, 0.f, 0.f, 0.f, 0.f, 0.f};
#pragma unroll
    for (int dd = 0; dd < 8; ++dd) {
        float4 wa = *(const float4*)(wgr + dd * N_EXP);
        float4 wb = *(const float4*)(wgr + dd * N_EXP + 4);
        acc[0] = fmaf(xv[dd], wa.x, acc[0]);
        acc[1] = fmaf(xv[dd], wa.y, acc[1]);
        acc[2] = fmaf(xv[dd], wa.z, acc[2]);
        acc[3] = fmaf(xv[dd], wa.w, acc[3]);
        acc[4] = fmaf(xv[dd], wb.x, acc[4]);
        acc[5] = fmaf(xv[dd], wb.y, acc[5]);
        acc[6] = fmaf(xv[dd], wb.z, acc[6]);
        acc[7] = fmaf(xv[dd], wb.w, acc[7]);
    }
#pragma unroll
    for (int off = 32; off >= 1; off >>= 1) {
#pragma unroll
        for (int e = 0; e < N_EXP; ++e)
            acc[e] += __shfl_xor(acc[e], off);
    }

    float g[8];
    float mx = -3.4e38f;
#pragma unroll
    for (int e = 0; e < N_EXP; ++e) { g[e] = acc[e] + bg[e]; mx = fmaxf(mx, g[e]); }
    float s = 0.f;
#pragma unroll
    for (int e = 0; e < N_EXP; ++e) { g[e] = expf(g[e] - mx); s += g[e]; }
    const float inv = 1.0f / s;
#pragma unroll
    for (int e = 0; e < N_EXP; ++e) g[e] *= inv;

    if (l == 0) {
        float* go = gates + (size_t)n * N_EXP;
        *(float4*)go       = make_float4(g[0], g[1], g[2], g[3]);
        *(float4*)(go + 4) = make_float4(g[4], g[5], g[6], g[7]);

        int e1 = 0; float g1 = g[0];
#pragma unroll
        for (int e = 1; e < N_EXP; ++e) if (g[e] > g1) { g1 = g[e]; e1 = e; }
        int e2 = -1; float g2 = -1.f;
#pragma unroll
        for (int e = 0; e < N_EXP; ++e) if (e != e1 && g[e] > g2) { g2 = g[e]; e2 = e; }

        recE[n] = make_int2(e1, e2);
        recG[n] = make_float2(g1, g2);
    }
}

// ---------------------------------------------------------------------------
// Prep: fused transpose-to-bf16 (blocks < nconv) + gating (blocks >= nconv).
// conv z<8: W1[e][D][H] -> w1t[e][H][D];  z>=8: W2[e][H][D] -> w2t[e][D][H].
// gate: 4 waves/block, one token per wave.
// ---------------------------------------------------------------------------
__global__ __launch_bounds__(256) void moe_prep(
    const float* __restrict__ W1, const float* __restrict__ W2,
    u16* __restrict__ w1t, u16* __restrict__ w2t, int nconv,
    const float* __restrict__ x, const float* __restrict__ Wg,
    const float* __restrict__ bg, float* __restrict__ gates,
    int2* __restrict__ recE, float2* __restrict__ recG,
    u16* __restrict__ xb, int write_xb)
{
    __shared__ u16 th[64][65];
    const int idx = blockIdx.x;
    if (idx < nconv) {
        const int z  = idx >> 8;            // 0..15
        const int e  = z & 7;
        const bool isW2 = z >= 8;
        const float* in = isW2 ? W2 : W1;
        u16* ob         = isW2 ? w2t : w1t;
        const int R = isW2 ? H_DIM : D_IN;
        const int C = isW2 ? D_IN : H_DIM;
        const size_t base = (size_t)e * R * C;
        const int rem = idx & 255;
        const int bx = rem & 31, by = rem >> 5;
        const int c0 = (isW2 ? by : bx) * 64;
        const int r0 = (isW2 ? bx : by) * 64;
        const int c  = threadIdx.x & 63, rq = threadIdx.x >> 6;

#pragma unroll
        for (int i = 0; i < 16; ++i) {
            int r = rq * 16 + i;
            th[r][c] = bf16_rne(in[base + (size_t)(r0 + r) * C + c0 + c]);
        }
        __syncthreads();
#pragma unroll
        for (int i = 0; i < 16; ++i) {
            int rw = rq * 16 + i;
            ob[base + (size_t)(c0 + rw) * R + r0 + c] = th[c][rw];
        }
    } else {
        const int g = idx - nconv;
        const int n = g * 4 + (threadIdx.x >> 6);
        const int l = threadIdx.x & 63;
        gate_one(n, l, x, Wg, bg, gates, recE, recG, xb, write_xb);
    }
}

// ---------------------------------------------------------------------------
// List build: 64 blocks. Block handles (expert e = bid>>3, 512-token chunk).
// LDS compaction, one global atomicAdd for the base. counts pre-zeroed.
// ---------------------------------------------------------------------------
__global__ __launch_bounds__(256) void build_lists(
    const int2* __restrict__ recE, const float2* __restrict__ recG,
    int* __restrict__ counts, int* __restrict__ lists, float* __restrict__ cwA,
    int* __restrict__ slotRec)
{
    __shared__ int cnt, base;
    __shared__ int   ltok[512];
    __shared__ float lcw[512];
    __shared__ int   lsrc[512];
    const int e  = blockIdx.x >> 3;
    const int c0 = (blockIdx.x & 7) * 512;
    const int tid = threadIdx.x;
    if (tid == 0) cnt = 0;
    __syncthreads();
#pragma unroll
    for (int it = 0; it < 2; ++it) {
        int t = c0 + it * 256 + tid;
        int2   ee = recE[t];
        float2 gg = recG[t];
        if (ee.x == e) {
            int p = atomicAdd(&cnt, 1);
            ltok[p] = t;  lcw[p] = gg.x;  lsrc[p] = 2 * t;
        }
        if (ee.y == e) {
            int p = atomicAdd(&cnt, 1);
            ltok[p] = t;  lcw[p] = gg.y;  lsrc[p] = 2 * t + 1;
        }
    }
    __syncthreads();
    if (tid == 0) base = atomicAdd(&counts[e], cnt);
    __syncthreads();
    const int c = cnt, b0 = base;
    for (int i = tid; i < c; i += 256) {
        int p = b0 + i;
        lists[e * N_TOK + p] = ltok[i];
        cwA[e * N_TOK + p]   = lcw[i];
        if (slotRec) slotRec[lsrc[i]] = p;
    }
}

// ---------------------------------------------------------------------------
// v8 expert kernel: full-H per block, counted-vmcnt triple-buffer pipeline.
//   e = blockIdx&7 (XCD affinity), t = blockIdx>>3.
//   per si in 0..7: prologue stage (drain once) then
//     G1 steps u=0..15:  wait vmcnt(5/4); s_barrier; stage g[u+2]; 8 MFMA
//     epilogue-1 -> hT (bias+relu, bf16)
//     G2 steps u=0..15:  wait vmcnt(4);   s_barrier; stage g[u+2]; 8 MFMA
//   accY[4][2][2] f32x4 persistent (y[32][512] in regs). Dense y stores.
// LDS: sB 48KB (3x16KB) + sA 6KB + hT 16.5KB = ~71KB -> 2 blocks/CU.
// ---------------------------------------------------------------------------
#define STG1(si_, ks_, buf_)                                                  \
    do {                                                                      \
        const u16* _s = w1E + (size_t)(si_) * (HS * D_IN) + (ks_) * 32;       \
        _Pragma("unroll")                                                     \
        for (int _i = 0; _i < 4; ++_i)                                        \
            async16(_s + bOffB[_i], &sB[buf_][dstB + _i * 512]);              \
        if (w < 2)                                                            \
            async16(xb + aOffW + (ks_) * 32, &sA[buf_][w * 512 + lane * 8]);  \
    } while (0)

#define STG2(si_, u2_, buf_)                                                  \
    do {                                                                      \
        const int _nc = (u2_) >> 2, _k2 = (u2_) & 3;                          \
        const u16* _s = w2E + (size_t)_nc * (128 * H_DIM) + (si_) * HS + _k2 * 64; \
        _Pragma("unroll")                                                     \
        for (int _i = 0; _i < 4; ++_i)                                        \
            async16(_s + bOff2[_i], &sB[buf_][dstB + _i * 512]);              \
    } while (0)

#define BARX do { __builtin_amdgcn_s_barrier();                               \
                  __builtin_amdgcn_sched_barrier(0); } while (0)

__global__ __launch_bounds__(256, 2) void moe_expert_mfma2(
    const u16* __restrict__ xb,
    const u16* __restrict__ w1t, const u16* __restrict__ w2t,
    const float* __restrict__ b1, const float* __restrict__ b2,
    float* __restrict__ y,
    const int* __restrict__ counts, const int* __restrict__ lists,
    const float* __restrict__ cwA)
{
    const int b = blockIdx.x;
    const int e = b & 7;            // expert -> XCD affinity
    const int t = b >> 3;
    int cnt = counts[e];
    if (cnt > YROWS) cnt = YROWS;
    if (t * TM >= cnt) return;

    __shared__ __align__(16) u16 sB[3][8192];    // 48 KB: 3x16KB chunks
    __shared__ __align__(16) u16 sA[3][1024];    //  6 KB: 3x2KB x chunks
    __shared__ __align__(16) u16 hT[TM * HROW];  // 16.5 KB
    __shared__ int   tokS[TM];
    __shared__ float cwS[TM];

    const int tid  = threadIdx.x;
    const int w    = tid >> 6;
    const int lane = tid & 63;
    const int quad = lane >> 4;
    const int l16  = lane & 15;

    if (tid < TM) {
        int gi = t * TM + tid;
        bool v = gi < cnt;
        tokS[tid] = v ? lists[e * N_TOK + gi] : 0;
        cwS[tid]  = v ? cwA[e * N_TOK + gi] : 0.f;   // cw=0 kills pad rows
    }
    __syncthreads();

    // ---- staging geometry (lds dest = wave base + lane*16B) ----
    const int r4   = lane >> 2;                       // G1: 16 rows/inst
    const int csw1 = (lane & 3) ^ ((lane >> 4) & 3);  // key=(rowInChunk>>2)&3
    const int r8   = lane >> 3;                       // G2: 8 rows/inst
    const int csw2 = (lane & 7) ^ r8;                 // key=rowInChunk&7
    const int dstB = w * 2048 + lane * 8;             // u16 offset in sB buf

    // ---- fragment read offsets (u16 elements, within a buffer) ----
    int fB1[4], fA1[2];
#pragma unroll
    for (int nt = 0; nt < 4; ++nt) {
        int r = w * 64 + nt * 16 + l16;
        fB1[nt] = r * 32 + (quad ^ ((l16 >> 2) & 3)) * 8;
    }
#pragma unroll
    for (int m = 0; m < 2; ++m) {
        int r = m * 16 + l16;
        fA1[m] = r * 32 + (quad ^ ((l16 >> 2) & 3)) * 8;
    }
    int fB2[2][2], fA2[2];
#pragma unroll
    for (int nt = 0; nt < 2; ++nt)
#pragma unroll
        for (int kk = 0; kk < 2; ++kk) {
            int r = w * 32 + nt * 16 + l16;
            fB2[nt][kk] = r * 64 + (((kk * 4 + quad) ^ (l16 & 7)) * 8);
        }
#pragma unroll
    for (int m = 0; m < 2; ++m)
        fA2[m] = (m * 16 + l16) * HROW + quad * 8;

    // ---- global staging offsets ----
    const u16* w1E = w1t + (size_t)e * H_DIM * D_IN;
    const u16* w2E = w2t + (size_t)e * D_IN * H_DIM;
    int bOffB[4];
#pragma unroll
    for (int i = 0; i < 4; ++i)
        bOffB[i] = (w * 64 + i * 16 + r4) * D_IN + csw1 * 8;
    int bOff2[4];
#pragma unroll
    for (int i = 0; i < 4; ++i)
        bOff2[i] = (w * 32 + i * 8 + r8) * H_DIM + csw2 * 8;
    int aOffW = 0;
    if (w < 2) aOffW = tokS[w * 16 + r4] * D_IN + csw1 * 8;

    // ---- persistent output accumulator: y[32][512] across all si ----
    f32x4 accY[4][2][2];
#pragma unroll
    for (int nc = 0; nc < 4; ++nc)
#pragma unroll
        for (int m = 0; m < 2; ++m)
#pragma unroll
            for (int nt = 0; nt < 2; ++nt)
                accY[nc][m][nt] = (f32x4){0.f, 0.f, 0.f, 0.f};

    for (int si = 0; si < 8; ++si) {
        // bias slice loads early (oldest vmem -> drained by u=0 wait)
        float b1v[4];
#pragma unroll
        for (int nt = 0; nt < 4; ++nt)
            b1v[nt] = b1[e * H_DIM + si * HS + w * 64 + nt * 16 + l16];

        // per-si pipeline refill: stage g1_0 -> b0 (b0 last read si-1 G2 u=14,
        // collectively before si-1 G2 u=15's barrier)
        STG1(si, 0, 0);

        // -------- GEMM1: h[32][256] = xb-tile @ W1T-slice(si) --------
        f32x4 acc1[2][4];
#pragma unroll
        for (int m = 0; m < 2; ++m)
#pragma unroll
            for (int nt = 0; nt < 4; ++nt) acc1[m][nt] = (f32x4){0.f, 0.f, 0.f, 0.f};

#pragma unroll
        for (int u = 0; u < 16; ++u) {
            // wait: leave only the newest staged group in flight
            if (u == 0) {
                asm volatile("s_waitcnt vmcnt(0)" ::: "memory");
            } else if (u < 15) {
                if (w < 2) asm volatile("s_waitcnt vmcnt(5)" ::: "memory");
                else       asm volatile("s_waitcnt vmcnt(4)" ::: "memory");
            } else {
                asm volatile("s_waitcnt vmcnt(4)" ::: "memory");
            }
            BARX;
            // stage ahead (target buffer last read 2 steps ago, barrier-safe)
            if (u == 0)       { STG1(si, 1, 1); STG1(si, 2, 2); }
            else if (u < 14)  { STG1(si, u + 2, (u + 2) % 3); }
            else if (u == 14) { STG2(si, 0, 1); }
            else              { STG2(si, 1, 2); }

            const u16* Bp = &sB[u % 3][0];
            const u16* Ap = &sA[u % 3][0];
            short8 bf[4], af[2];
#pragma unroll
            for (int nt = 0; nt < 4; ++nt) bf[nt] = *(const short8*)(Bp + fB1[nt]);
#pragma unroll
            for (int m = 0; m < 2; ++m)  af[m] = *(const short8*)(Ap + fA1[m]);
            __builtin_amdgcn_s_setprio(1);
#pragma unroll
            for (int nt = 0; nt < 4; ++nt)
#pragma unroll
                for (int m = 0; m < 2; ++m)
                    acc1[m][nt] = __builtin_amdgcn_mfma_f32_16x16x32_bf16(
                        af[m], bf[nt], acc1[m][nt], 0, 0, 0);
            __builtin_amdgcn_s_setprio(0);
        }

        // -------- epilogue 1: bias + relu -> hT (bf16) --------
#pragma unroll
        for (int nt = 0; nt < 4; ++nt) {
            const int c = w * 64 + nt * 16 + l16;
#pragma unroll
            for (int m = 0; m < 2; ++m)
#pragma unroll
                for (int r = 0; r < 4; ++r) {
                    int row = m * 16 + quad * 4 + r;
                    hT[row * HROW + c] = bf16_rne(fmaxf(acc1[m][nt][r] + b1v[nt], 0.f));
                }
        }

        // -------- GEMM2: accY += hT @ W2T-slice(si) --------
#pragma unroll
        for (int u = 0; u < 16; ++u) {
            if (u == 0)      asm volatile("s_waitcnt vmcnt(4) lgkmcnt(0)" ::: "memory");
            else if (u < 15) asm volatile("s_waitcnt vmcnt(4)" ::: "memory");
            else             asm volatile("s_waitcnt vmcnt(0)" ::: "memory");
            BARX;
            if (u < 14) STG2(si, u + 2, u % 3);

            const int nc = u >> 2, k2 = u & 3;
            const u16* Bp = &sB[(u + 1) % 3][0];
#pragma unroll
            for (int kk = 0; kk < 2; ++kk) {
                short8 a0  = *(const short8*)(hT + fA2[0] + k2 * 64 + kk * 32);
                short8 a1  = *(const short8*)(hT + fA2[1] + k2 * 64 + kk * 32);
                short8 b0  = *(const short8*)(Bp + fB2[0][kk]);
                short8 b1f = *(const short8*)(Bp + fB2[1][kk]);
                __builtin_amdgcn_s_setprio(1);
                accY[nc][0][0] = __builtin_amdgcn_mfma_f32_16x16x32_bf16(a0, b0,  accY[nc][0][0], 0, 0, 0);
                accY[nc][1][0] = __builtin_amdgcn_mfma_f32_16x16x32_bf16(a1, b0,  accY[nc][1][0], 0, 0, 0);
                accY[nc][0][1] = __builtin_amdgcn_mfma_f32_16x16x32_bf16(a0, b1f, accY[nc][0][1], 0, 0, 0);
                accY[nc][1][1] = __builtin_amdgcn_mfma_f32_16x16x32_bf16(a1, b1f, accY[nc][1][1], 0, 0, 0);
                __builtin_amdgcn_s_setprio(0);
            }
        }
    }

    // -------- epilogue: dense y write: (acc + b2) * cw --------
    float* yT = y + ((size_t)e * YROWS + (size_t)t * TM) * D_IN;
#pragma unroll
    for (int nc = 0; nc < 4; ++nc)
#pragma unroll
        for (int nt = 0; nt < 2; ++nt) {
            const int dcol = nc * 128 + w * 32 + nt * 16 + l16;
            const float bias = b2[e * D_IN + dcol];
#pragma unroll
            for (int m = 0; m < 2; ++m)
#pragma unroll
                for (int r = 0; r < 4; ++r) {
                    const int row = m * 16 + quad * 4 + r;
                    yT[(size_t)row * D_IN + dcol] =
                        (accY[nc][m][nt][r] + bias) * cwS[row];
                }
        }
}

// ---------------------------------------------------------------------------
// Combine: out[t] = y[e1][slot1] + y[e2][slot2]   (cw, b2 already folded in).
// ---------------------------------------------------------------------------
__global__ __launch_bounds__(256) void moe_combine(
    const float* __restrict__ y, const int* __restrict__ slotRec,
    const int2* __restrict__ recE, float* __restrict__ out)
{
    const int t  = blockIdx.x * 2 + (threadIdx.x >> 7);
    const int c4 = (threadIdx.x & 127) << 2;
    const int2 ee = recE[t];
    int s1 = slotRec[2 * t + 0];
    int s2 = slotRec[2 * t + 1];
    s1 = s1 < YROWS ? s1 : YROWS - 1;   // safety clamp
    s2 = s2 < YROWS ? s2 : YROWS - 1;
    const float4 a  = *(const float4*)(y + ((size_t)ee.x * YROWS + s1) * D_IN + c4);
    const float4 bb = *(const float4*)(y + ((size_t)ee.y * YROWS + s2) * D_IN + c4);
    *(float4*)(out + (size_t)t * D_IN + c4) =
        make_float4(a.x + bb.x, a.y + bb.y, a.z + bb.z, a.w + bb.w);
}

// ---------------------------------------------------------------------------
// r6 single-pass bf16 expert kernel (known-passing) — fallback if ws < NEED2.
// ---------------------------------------------------------------------------
__global__ __launch_bounds__(256, 4) void moe_expert_mfma(
    const u16* __restrict__ xb,
    const u16* __restrict__ w1t, const u16* __restrict__ w2t,
    const float* __restrict__ b1, const float* __restrict__ b2,
    float* __restrict__ out,
    const int* __restrict__ counts, const int* __restrict__ lists,
    const float* __restrict__ cwA)
{
    const int b = blockIdx.x;
    const int s = b & 7;
    const int q = b >> 3;
    const int t = q % MAXT;
    const int e = q / MAXT;
    const int cnt = counts[e];
    if (t * TM >= cnt) return;

    __shared__ __align__(16) u16 sB[8192];
    __shared__ __align__(16) u16 sA[1024];
    __shared__ __align__(16) u16 hT[TM * HROW];
    __shared__ int   tokS[TM];
    __shared__ float cwS[TM];

    const int tid  = threadIdx.x;
    const int w    = tid >> 6;
    const int lane = tid & 63;
    const int quad = lane >> 4;
    const int l16  = lane & 15;

    if (tid < TM) {
        int gi = t * TM + tid;
        bool v = gi < cnt;
        tokS[tid] = v ? lists[e * N_TOK + gi] : 0;
        cwS[tid]  = v ? cwA[e * N_TOK + gi] : 0.f;
    }
    __syncthreads();

    const int r4   = lane >> 2;
    const int csw1 = (lane & 3) ^ ((lane >> 4) & 3);
    const int r8   = lane >> 3;
    const int csw2 = (lane & 7) ^ r8;
    u16* ldsB0 = sB + w * 2048 + lane * 8;
    u16* ldsA0 = sA + lane * 8;

    int fB1[4], fA1[2];
#pragma unroll
    for (int nt = 0; nt < 4; ++nt) {
        int r = w * 64 + nt * 16 + l16;
        fB1[nt] = r * 32 + (quad ^ ((l16 >> 2) & 3)) * 8;
    }
#pragma unroll
    for (int m = 0; m < 2; ++m) {
        int r = m * 16 + l16;
        fA1[m] = r * 32 + (quad ^ ((l16 >> 2) & 3)) * 8;
    }
    int fB2[2][2], fA2[2];
#pragma unroll
    for (int nt = 0; nt < 2; ++nt)
#pragma unroll
        for (int kk = 0; kk < 2; ++kk) {
            int r = w * 32 + nt * 16 + l16;
            fB2[nt][kk] = r * 64 + (((kk * 4 + quad) ^ (l16 & 7)) * 8);
        }
#pragma unroll
    for (int m = 0; m < 2; ++m)
        fA2[m] = (m * 16 + l16) * HROW + quad * 8;

    int bOffB[4];
#pragma unroll
    for (int i = 0; i < 4; ++i)
        bOffB[i] = (s * HS + w * 64 + i * 16 + r4) * D_IN + csw1 * 8;
    int aOff0 = tokS[r4]      * D_IN + csw1 * 8;
    int aOff1 = tokS[16 + r4] * D_IN + csw1 * 8;
    const u16* w1E = w1t + (size_t)e * H_DIM * D_IN;

    f32x4 acc1[2][4];
#pragma unroll
    for (int m = 0; m < 2; ++m)
#pragma unroll
        for (int nt = 0; nt < 4; ++nt) acc1[m][nt] = (f32x4){0.f, 0.f, 0.f, 0.f};

    for (int ks = 0; ks < 16; ++ks) {
        const int kb = ks * 32;
        __syncthreads();
#pragma unroll
        for (int i = 0; i < 4; ++i)
            async16(w1E + bOffB[i] + kb, ldsB0 + i * 512);
        if (w == 0) {
            async16(xb + aOff0 + kb, ldsA0);
            async16(xb + aOff1 + kb, ldsA0 + 512);
        }
        __syncthreads();
        short8 bf[4], af[2];
#pragma unroll
        for (int nt = 0; nt < 4; ++nt) bf[nt] = *(const short8*)(sB + fB1[nt]);
#pragma unroll
        for (int m = 0; m < 2; ++m)  af[m] = *(const short8*)(sA + fA1[m]);
#pragma unroll
        for (int nt = 0; nt < 4; ++nt)
#pragma unroll
            for (int m = 0; m < 2; ++m)
                acc1[m][nt] = __builtin_amdgcn_mfma_f32_16x16x32_bf16(af[m], bf[nt], acc1[m][nt], 0, 0, 0);
    }

#pragma unroll
    for (int nt = 0; nt < 4; ++nt) {
        const int c = w * 64 + nt * 16 + l16;
        const float bias = b1[e * H_DIM + s * HS + c];
#pragma unroll
        for (int m = 0; m < 2; ++m)
#pragma unroll
            for (int r = 0; r < 4; ++r) {
                int row = m * 16 + quad * 4 + r;
                hT[row * HROW + c] = bf16_rne(fmaxf(acc1[m][nt][r] + bias, 0.f));
            }
    }

    const u16* w2E = w2t + (size_t)e * D_IN * H_DIM;
    int bOff2[4];
#pragma unroll
    for (int i = 0; i < 4; ++i)
        bOff2[i] = (w * 32 + i * 8 + r8) * H_DIM + s * HS + csw2 * 8;

    for (int nc = 0; nc < 4; ++nc) {
        f32x4 acc2[2][2];
#pragma unroll
        for (int m = 0; m < 2; ++m)
#pragma unroll
            for (int nt = 0; nt < 2; ++nt) acc2[m][nt] = (f32x4){0.f, 0.f, 0.f, 0.f};

        for (int ks = 0; ks < 4; ++ks) {
            __syncthreads();
#pragma unroll
            for (int i = 0; i < 4; ++i)
                async16(w2E + bOff2[i] + nc * (128 * H_DIM) + ks * 64,
                        ldsB0 + i * 512);
            __syncthreads();
#pragma unroll
            for (int kk = 0; kk < 2; ++kk) {
                short8 a0  = *(const short8*)(hT + fA2[0] + ks * 64 + kk * 32);
                short8 a1  = *(const short8*)(hT + fA2[1] + ks * 64 + kk * 32);
                short8 b0  = *(const short8*)(sB + fB2[0][kk]);
                short8 b1f = *(const short8*)(sB + fB2[1][kk]);
                acc2[0][0] = __builtin_amdgcn_mfma_f32_16x16x32_bf16(a0, b0,  acc2[0][0], 0, 0, 0);
                acc2[1][0] = __builtin_amdgcn_mfma_f32_16x16x32_bf16(a1, b0,  acc2[1][0], 0, 0, 0);
                acc2[0][1] = __builtin_amdgcn_mfma_f32_16x16x32_bf16(a0, b1f, acc2[0][1], 0, 0, 0);
                acc2[1][1] = __builtin_amdgcn_mfma_f32_16x16x32_bf16(a1, b1f, acc2[1][1], 0, 0, 0);
            }
        }

#pragma unroll
        for (int nt = 0; nt < 2; ++nt) {
            const int dcol = nc * 128 + w * 32 + nt * 16 + l16;
            const float bias = (s == 0) ? b2[e * D_IN + dcol] : 0.f;
#pragma unroll
            for (int m = 0; m < 2; ++m)
#pragma unroll
                for (int r = 0; r < 4; ++r) {
                    int row = m * 16 + quad * 4 + r;
                    float v = (acc2[m][nt][r] + bias) * cwS[row];
                    atomicAdd(out + (size_t)tokS[row] * D_IN + dcol, v);
                }
        }
    }
}

// ---------------------------------------------------------------------------
// Fallback fp32 expert kernel (round 1, known-passing) — used if ws too small.
// ---------------------------------------------------------------------------
__global__ __launch_bounds__(256, 4) void moe_expert_fp32(
    const float* __restrict__ x,  const float* __restrict__ W1,
    const float* __restrict__ b1, const float* __restrict__ W2,
    const float* __restrict__ b2, float* __restrict__ out,
    const int* __restrict__ counts, const int* __restrict__ lists,
    const float* __restrict__ cwA)
{
    const int e    = blockIdx.x & 7;
    const int tile = blockIdx.x >> 3;
    const int cnt  = counts[e];
    if (tile * 16 >= cnt) return;

    __shared__ float xs[16 * 520];
    __shared__ float hs[16 * 68];
    __shared__ int   tokS[16];
    __shared__ float cwS[16];

    const int tid = threadIdx.x;
    if (tid < 16) {
        int gi = tile * 16 + tid;
        bool v = gi < cnt;
        tokS[tid] = v ? lists[e * N_TOK + gi] : 0;
        cwS[tid]  = v ? cwA[e * N_TOK + gi]  : 0.f;
    }
    __syncthreads();
    {
        const int i = tid >> 4, p = tid & 15;
        const float* xr = x + (size_t)tokS[i] * D_IN + p * 32;
        float* xd = xs + i * 520 + p * 32;
#pragma unroll
        for (int qq = 0; qq < 8; ++qq)
            *(float4*)(xd + qq * 4) = *(const float4*)(xr + qq * 4);
    }
    __syncthreads();

    const float* W1e = W1 + (size_t)e * D_IN * H_DIM;
    const float* W2e = W2 + (size_t)e * H_DIM * D_IN;
    const int j = tid & 31, rg1 = tid >> 5, cg = tid & 63, rg2 = tid >> 6;

    float acc[4][8];
#pragma unroll
    for (int i = 0; i < 4; ++i)
#pragma unroll
        for (int m = 0; m < 8; ++m) acc[i][m] = 0.f;

    for (int hc = 0; hc < H_DIM / 64; ++hc) {
        float a1[2][2] = {{0.f, 0.f}, {0.f, 0.f}};
        const float* w1p = W1e + hc * 64 + j;
        for (int d = 0; d < D_IN; d += 4) {
            float xv[2][4];
            *(float4*)xv[0] = *(const float4*)(xs + (rg1 * 2 + 0) * 520 + d);
            *(float4*)xv[1] = *(const float4*)(xs + (rg1 * 2 + 1) * 520 + d);
#pragma unroll
            for (int dd = 0; dd < 4; ++dd) {
                float wa = w1p[(size_t)(d + dd) * H_DIM];
                float wb = w1p[(size_t)(d + dd) * H_DIM + 32];
                a1[0][0] = fmaf(xv[0][dd], wa, a1[0][0]);
                a1[0][1] = fmaf(xv[0][dd], wb, a1[0][1]);
                a1[1][0] = fmaf(xv[1][dd], wa, a1[1][0]);
                a1[1][1] = fmaf(xv[1][dd], wb, a1[1][1]);
            }
        }
        float b1a = b1[e * H_DIM + hc * 64 + j];
        float b1b = b1[e * H_DIM + hc * 64 + j + 32];
        __syncthreads();
        hs[(rg1 * 2 + 0) * 68 + j]      = fmaxf(a1[0][0] + b1a, 0.f);
        hs[(rg1 * 2 + 0) * 68 + j + 32] = fmaxf(a1[0][1] + b1b, 0.f);
        hs[(rg1 * 2 + 1) * 68 + j]      = fmaxf(a1[1][0] + b1a, 0.f);
        hs[(rg1 * 2 + 1) * 68 + j + 32] = fmaxf(a1[1][1] + b1b, 0.f);
        __syncthreads();
        const float* w2p = W2e + (size_t)(hc * 64) * D_IN + cg;
        for (int k = 0; k < 64; k += 4) {
            float hv[4][4];
#pragma unroll
            for (int i = 0; i < 4; ++i)
                *(float4*)hv[i] = *(const float4*)(hs + (rg2 * 4 + i) * 68 + k);
#pragma unroll
            for (int kk = 0; kk < 4; ++kk) {
                float w2r[8];
#pragma unroll
                for (int m = 0; m < 8; ++m)
                    w2r[m] = w2p[(size_t)(k + kk) * D_IN + 64 * m];
#pragma unroll
                for (int i = 0; i < 4; ++i)
#pragma unroll
                    for (int m = 0; m < 8; ++m)
                        acc[i][m] = fmaf(hv[i][kk], w2r[m], acc[i][m]);
            }
        }
        __syncthreads();
    }
    float b2v[8];
#pragma unroll
    for (int m = 0; m < 8; ++m) b2v[m] = b2[e * D_IN + cg + 64 * m];
#pragma unroll
    for (int i = 0; i < 4; ++i) {
        const int r = rg2 * 4 + i;
        const float cw = cwS[r];
        float* op = out + (size_t)tokS[r] * D_IN + cg;
#pragma unroll
        for (int m = 0; m < 8; ++m)
            atomicAdd(op + 64 * m, (acc[i][m] + b2v[m]) * cw);
    }
}

// ---------------------------------------------------------------------------
extern "C" void kernel_launch(void* const* d_in, const int* in_sizes, int n_in,
                              void* d_out, int out_size, void* d_ws, size_t ws_size,
                              hipStream_t stream) {
    const float* x  = (const float*)d_in[0];
    const float* Wg = (const float*)d_in[1];
    const float* bg = (const float*)d_in[2];
    const float* W1 = (const float*)d_in[3];
    const float* b1 = (const float*)d_in[4];
    const float* W2 = (const float*)d_in[5];
    const float* b2 = (const float*)d_in[6];

    float* out   = (float*)d_out;
    float* gates = out + (size_t)N_TOK * D_IN;

    // ws layout: counts | recE | recG | lists | cw | xb | w1t | w2t | slot | y
    const size_t o_recE  = 1024;
    const size_t o_recG  = o_recE + (size_t)N_TOK * 8;
    const size_t o_lists = o_recG + (size_t)N_TOK * 8;
    const size_t o_cw    = o_lists + (size_t)N_EXP * N_TOK * 4;
    const size_t o_xb    = o_cw + (size_t)N_EXP * N_TOK * 4;
    const size_t o_w1t   = o_xb + (size_t)N_TOK * D_IN * 2;
    const size_t o_w2t   = o_w1t + (size_t)N_EXP * D_IN * H_DIM * 2;
    const size_t o_slot  = o_w2t + (size_t)N_EXP * D_IN * H_DIM * 2;
    const size_t o_y     = o_slot + (size_t)N_TOK * 2 * 4;
    const size_t NEED1   = o_slot;                                   // ~38.1 MB
    const size_t NEED2   = o_y + (size_t)N_EXP * YROWS * D_IN * 4;   // ~56.4 MB

    int*    counts  = (int*)d_ws;
    int2*   recE    = (int2*)((char*)d_ws + o_recE);
    float2* recG    = (float2*)((char*)d_ws + o_recG);
    int*    lists   = (int*)((char*)d_ws + o_lists);
    float*  cwA     = (float*)((char*)d_ws + o_cw);
    u16*    xb      = (u16*)((char*)d_ws + o_xb);
    u16*    w1t    = (u16*)((char*)d_ws + o_w1t);
    u16*    w2t    = (u16*)((char*)d_ws + o_w2t);
    int*    slotRec = (int*)((char*)d_ws + o_slot);
    float*  yws     = (float*)((char*)d_ws + o_y);

    const int mode = (ws_size >= NEED2) ? 2 : (ws_size >= NEED1 ? 1 : 0);
    const int nconv = (mode >= 1) ? 4096 : 0;
    const int nprep = nconv + N_TOK / 4;      // gate: 4 tokens/block, 4 waves

    hipMemsetAsync(d_ws, 0, 1024, stream);    // zero counts (atomic bases)

    moe_prep<<<nprep, 256, 0, stream>>>(
        W1, W2, w1t, w2t, nconv,
        x, Wg, bg, gates, recE, recG, xb, mode >= 1 ? 1 : 0);
    build_lists<<<64, 256, 0, stream>>>(recE, recG, counts, lists, cwA,
                                        mode == 2 ? slotRec : (int*)nullptr);

    if (mode == 2) {
        moe_expert_mfma2<<<N_EXP * MAXT, 256, 0, stream>>>(
            xb, w1t, w2t, b1, b2, yws, counts, lists, cwA);
        moe_combine<<<N_TOK / 2, 256, 0, stream>>>(yws, slotRec, recE, out);
    } else if (mode == 1) {
        hipMemsetAsync(d_out, 0, (size_t)N_TOK * D_IN * sizeof(float), stream);
        moe_expert_mfma<<<N_EXP * MAXT * 8, 256, 0, stream>>>(
            xb, w1t, w2t, b1, b2, out, counts, lists, cwA);
    } else {
        hipMemsetAsync(d_out, 0, (size_t)N_TOK * D_IN * sizeof(float), stream);
        moe_expert_fp32<<<N_EXP * 256, 256, 0, stream>>>(
            x, W1, b1, W2, b2, out, counts, lists, cwA);
    }
}